// Round 1
// 386.364 us; speedup vs baseline: 1.0322x; 1.0322x over previous
//
#include <hip/hip_runtime.h>
#include <math.h>

#define BB 4
#define SS 2048
#define DD 1024
#define MM (BB*SS)                   // 8192
#define SD ((size_t)SS*DD)
#define MD ((size_t)MM*DD)           // 8,388,608
#define PPB ((size_t)2162688)        // packed P elems per batch

// ws (bf16 elems): Q@0 | K@MD | VT@2MD | P@3MD (4*PPB) | WT@3MD+4PPB (6*DD*DD) | zpad(16)
#define WT_OFF (3*MD + 4*PPB)
#define ZP_OFF (WT_OFF + 6*(size_t)DD*DD)
#define REQ_WS ((ZP_OFF + 16) * 2)

constexpr float LN_EPS = 1e-6f;

typedef __attribute__((ext_vector_type(8))) __bf16 bf16x8;
typedef __attribute__((ext_vector_type(4))) float f32x4;

__device__ __forceinline__ unsigned short f2bfbits(float f){
    unsigned u = __float_as_uint(f);
    u += 0x7FFFu + ((u >> 16) & 1u);   // RNE
    return (unsigned short)(u >> 16);
}
__device__ __forceinline__ int rowWidth(int s){ return ((s >> 6) + 1) << 6; }
__device__ __forceinline__ size_t rowOff(int s){
    int g = s >> 6;
    return (size_t)4096 * (size_t)((g * (g + 1)) >> 1) + (size_t)(s & 63) * (size_t)((g + 1) << 6);
}
// async global->LDS, 16B per lane; LDS dest = wave-uniform base + lane*16
__device__ __forceinline__ void gl_lds(const unsigned short* g, unsigned short* l){
    __builtin_amdgcn_global_load_lds(
        (const __attribute__((address_space(1))) unsigned int*)g,
        (__attribute__((address_space(3))) unsigned int*)l, 16, 0, 0);
}

// XCD-aware bijective block swizzle (T1): each of the 8 XCDs gets a
// contiguous chunk of the linearized grid -> neighbor tiles share L2.
// Valid because every MFMA launch here has (gx*gy*gz) % 8 == 0.
__device__ __forceinline__ int3 xcd_swz(){
    const int gx = gridDim.x, gy = gridDim.y, gz = gridDim.z;
    const int n = gx * gy * gz;
    int lin = blockIdx.x + gx * (blockIdx.y + gy * blockIdx.z);
    const int cpx = n >> 3;                 // n % 8 == 0 for all launches
    lin = (lin & 7) * cpx + (lin >> 3);     // bijection: XCD (lin&7) owns chunk
    int3 r;
    r.x = lin % gx; lin /= gx;
    r.y = lin % gy;
    r.z = lin / gy;
    return r;
}

__global__ __launch_bounds__(256)
void sentinel_kernel(float* __restrict__ out, const float val){
    out[(size_t)blockIdx.x * 256 + threadIdx.x] = val;
}

// ---------- weight transpose W[K][N] f32 -> WT[N][K] bf16 ; also zeroes zpad ----------
struct WPack { const float* w[6]; unsigned short* o[6]; unsigned short* zp; };
__global__ __launch_bounds__(256)
void wtrans(WPack wp)
{
    __shared__ float Ts[64][65];
    const float* W = wp.w[blockIdx.z];
    unsigned short* WT = wp.o[blockIdx.z];
    const int r0 = blockIdx.y*64, c0 = blockIdx.x*64;
    const int tid = threadIdx.x;
    if (blockIdx.x == 0 && blockIdx.y == 0 && blockIdx.z == 0 && tid < 16) wp.zp[tid] = 0;
    #pragma unroll
    for (int i = 0; i < 16; ++i){
        int lin = tid + i*256;
        int r = lin >> 6, c = lin & 63;
        Ts[r][c] = W[(size_t)(r0+r)*DD + c0+c];
    }
    __syncthreads();
    #pragma unroll
    for (int i = 0; i < 16; ++i){
        int lin = tid + i*256;
        int r = lin >> 6, c = lin & 63;
        WT[(size_t)(c0+r)*DD + r0+c] = f2bfbits(Ts[c][r]);
    }
}

// ---------- LayerNorm: fp32 in -> bf16 out ----------
__global__ __launch_bounds__(256)
void ln_f32(const float* __restrict__ x, const float* __restrict__ gamma,
            const float* __restrict__ beta, unsigned short* __restrict__ out)
{
    __shared__ float red[4];
    const int row = blockIdx.x;
    const int tid = threadIdx.x;
    float4 xv = ((const float4*)(x + (size_t)row*DD))[tid];
    float v[4] = {xv.x, xv.y, xv.z, xv.w};
    float s = v[0]+v[1]+v[2]+v[3];
    #pragma unroll
    for (int off = 32; off > 0; off >>= 1) s += __shfl_down(s, off, 64);
    if ((tid & 63) == 0) red[tid >> 6] = s;
    __syncthreads();
    const float mean = (red[0]+red[1]+red[2]+red[3]) * (1.0f/DD);
    __syncthreads();
    float q = 0.f;
    #pragma unroll
    for (int i = 0; i < 4; ++i){ float d = v[i]-mean; q += d*d; }
    #pragma unroll
    for (int off = 32; off > 0; off >>= 1) q += __shfl_down(q, off, 64);
    if ((tid & 63) == 0) red[tid >> 6] = q;
    __syncthreads();
    const float var = (red[0]+red[1]+red[2]+red[3]) * (1.0f/(DD-1));
    const float inv = 1.0f/(sqrtf(var) + LN_EPS);
    float4 g4 = ((const float4*)gamma)[tid];
    float4 b4 = ((const float4*)beta)[tid];
    ushort4 o;
    o.x = f2bfbits(g4.x*(v[0]-mean)*inv + b4.x);
    o.y = f2bfbits(g4.y*(v[1]-mean)*inv + b4.y);
    o.z = f2bfbits(g4.z*(v[2]-mean)*inv + b4.z);
    o.w = f2bfbits(g4.w*(v[3]-mean)*inv + b4.w);
    ((ushort4*)(out + (size_t)row*DD))[tid] = o;
}

// =========== MFMA GEMM core: C[128,128] tile of A[M,K]*B[N,K]^T ===========
// BK=64, 4 waves 2x2, each 64x64. global_load_lds staging, granule-rotated LDS.
// LDS tile: row m (64 shorts), granule g stored at slot (g+m)&7.
template<bool RELU, bool RES, bool OUTF, bool BIAS_M>
__device__ __forceinline__ void gemm_core(
    const unsigned short* __restrict__ A, const unsigned short* __restrict__ B,
    const float* __restrict__ bias, const float* __restrict__ resF,
    unsigned short* __restrict__ outB, float* __restrict__ outF,
    const int N, const int K, const int lda, const int ldb,
    const int m0, const int n0,
    unsigned short* As, unsigned short* Bs)
{
    const int tid = threadIdx.x, lane = tid & 63, wave = tid >> 6;
    const int wm = ((wave >> 1) & 1) * 64, wn = (wave & 1) * 64;
    const int quad = lane >> 4, l15 = lane & 15;
    const unsigned short* ga[4]; const unsigned short* gb[4];
    #pragma unroll
    for (int c = 0; c < 4; ++c){
        const int mr = (wave*4 + c)*8 + (lane >> 3);
        const int gk = ((lane & 7) - mr) & 7;
        ga[c] = A + (size_t)(m0 + mr)*lda + gk*8;
        gb[c] = B + (size_t)(n0 + mr)*ldb + gk*8;
    }
    f32x4 acc[4][4] = {};
    for (int k0 = 0; k0 < K; k0 += 64){
        #pragma unroll
        for (int c = 0; c < 4; ++c){
            gl_lds(ga[c] + k0, &As[(wave*4+c)*512]);
            gl_lds(gb[c] + k0, &Bs[(wave*4+c)*512]);
        }
        __syncthreads();
        #pragma unroll
        for (int kk = 0; kk < 2; ++kk){
            bf16x8 af[4], bfr[4];
            #pragma unroll
            for (int t = 0; t < 4; ++t){
                const int ra = wm + t*16 + l15, rb = wn + t*16 + l15, gi = kk*4 + quad;
                af[t]  = *(const bf16x8*)&As[ra*64 + (((gi + ra) & 7) << 3)];
                bfr[t] = *(const bf16x8*)&Bs[rb*64 + (((gi + rb) & 7) << 3)];
            }
            #pragma unroll
            for (int i = 0; i < 4; ++i)
                #pragma unroll
                for (int j = 0; j < 4; ++j)
                    acc[i][j] = __builtin_amdgcn_mfma_f32_16x16x32_bf16(af[i], bfr[j], acc[i][j], 0, 0, 0);
        }
        __syncthreads();
    }
    #pragma unroll
    for (int i = 0; i < 4; ++i){
        #pragma unroll
        for (int r = 0; r < 4; ++r){
            const int m = m0 + wm + i*16 + quad*4 + r;
            const float bm = BIAS_M ? bias[m] : 0.f;
            #pragma unroll
            for (int j = 0; j < 4; ++j){
                const int n = n0 + wn + j*16 + l15;
                float v = acc[i][j][r] + (BIAS_M ? bm : bias[n]);
                if constexpr (RELU) v = fmaxf(v, 0.f);
                if constexpr (RES) v += resF[(size_t)m*N + n];
                if constexpr (OUTF) outF[(size_t)m*N + n] = v;
                else outB[(size_t)m*N + n] = f2bfbits(v);
            }
        }
    }
}

// generic single GEMM
template<bool RELU, bool RES, bool OUTF, bool BIAS_M>
__global__ __launch_bounds__(256)
void gemm_mfma(const unsigned short* __restrict__ A, const unsigned short* __restrict__ B,
               const float* __restrict__ bias, const float* __restrict__ resF,
               unsigned short* __restrict__ outB, float* __restrict__ outF,
               const int N, const int K, const int lda, const int ldb)
{
    __shared__ unsigned short As[128*64];
    __shared__ unsigned short Bs[128*64];
    const int3 b = xcd_swz();
    gemm_core<RELU,RES,OUTF,BIAS_M>(A, B, bias, resF, outB, outF, N, K, lda, ldb,
                                    b.y*128, b.x*128, As, Bs);
}

// merged Q+K projection (z=0 -> Q, z=1 -> K)
__global__ __launch_bounds__(256)
void gemm_qk(const unsigned short* __restrict__ LN,
             const unsigned short* __restrict__ WqT, const unsigned short* __restrict__ WkT,
             const float* __restrict__ bq, const float* __restrict__ bk,
             unsigned short* __restrict__ Qw, unsigned short* __restrict__ Kw)
{
    __shared__ unsigned short As[128*64];
    __shared__ unsigned short Bs[128*64];
    const int3 b = xcd_swz();
    const bool isK = (b.z != 0);
    gemm_core<false,false,false,false>(LN, isK ? WkT : WqT, isK ? bk : bq, nullptr,
                                       isK ? Kw : Qw, nullptr, DD, DD, DD, DD,
                                       b.y*128, b.x*128, As, Bs);
}

// ---------- scores: packed P = Q*K^T * scale (causal block-skip) ----------
__global__ __launch_bounds__(256)
void scores_mfma(const unsigned short* __restrict__ Qb, const unsigned short* __restrict__ Kb,
                 unsigned short* __restrict__ Pb, const float scale)
{
    const int3 b = xcd_swz();
    const int s0 = b.y*128, t0 = b.x*128;
    if (t0 > s0) return;
    const unsigned short* Q  = Qb + (size_t)b.z*SD;
    const unsigned short* Km = Kb + (size_t)b.z*SD;
    unsigned short* P        = Pb + (size_t)b.z*PPB;
    __shared__ unsigned short As[128*64];
    __shared__ unsigned short Bs[128*64];
    const int tid = threadIdx.x, lane = tid & 63, wave = tid >> 6;
    const int wm = ((wave >> 1) & 1) * 64, wn = (wave & 1) * 64;
    const int quad = lane >> 4, l15 = lane & 15;
    const unsigned short* ga[4]; const unsigned short* gb[4];
    #pragma unroll
    for (int c = 0; c < 4; ++c){
        const int mr = (wave*4 + c)*8 + (lane >> 3);
        const int gk = ((lane & 7) - mr) & 7;
        ga[c] = Q  + (size_t)(s0 + mr)*DD + gk*8;
        gb[c] = Km + (size_t)(t0 + mr)*DD + gk*8;
    }
    f32x4 acc[4][4] = {};
    for (int k0 = 0; k0 < DD; k0 += 64){
        #pragma unroll
        for (int c = 0; c < 4; ++c){
            gl_lds(ga[c] + k0, &As[(wave*4+c)*512]);
            gl_lds(gb[c] + k0, &Bs[(wave*4+c)*512]);
        }
        __syncthreads();
        #pragma unroll
        for (int kk = 0; kk < 2; ++kk){
            bf16x8 af[4], bfr[4];
            #pragma unroll
            for (int t = 0; t < 4; ++t){
                const int ra = wm + t*16 + l15, rb = wn + t*16 + l15, gi = kk*4 + quad;
                af[t]  = *(const bf16x8*)&As[ra*64 + (((gi + ra) & 7) << 3)];
                bfr[t] = *(const bf16x8*)&Bs[rb*64 + (((gi + rb) & 7) << 3)];
            }
            #pragma unroll
            for (int i = 0; i < 4; ++i)
                #pragma unroll
                for (int j = 0; j < 4; ++j)
                    acc[i][j] = __builtin_amdgcn_mfma_f32_16x16x32_bf16(af[i], bfr[j], acc[i][j], 0, 0, 0);
        }
        __syncthreads();
    }
    #pragma unroll
    for (int i = 0; i < 4; ++i){
        #pragma unroll
        for (int r = 0; r < 4; ++r){
            const int s = s0 + wm + i*16 + quad*4 + r;
            const int width = rowWidth(s);
            unsigned short* pr = P + rowOff(s);
            #pragma unroll
            for (int j = 0; j < 4; ++j){
                const int t = t0 + wn + j*16 + l15;
                if (t < width) pr[t] = f2bfbits(acc[i][j][r] * scale);
            }
        }
    }
}

// ---------- causal softmax over packed rows ----------
__global__ __launch_bounds__(256)
void softmax_p(unsigned short* __restrict__ Pb)
{
    __shared__ float red[4];
    const int s = blockIdx.x;
    const int width = rowWidth(s);
    unsigned short* r = Pb + (size_t)blockIdx.y * PPB + rowOff(s);
    const int tid = threadIdx.x;
    float vals[8];
    float m = -1e30f;
    #pragma unroll
    for (int i = 0; i < 8; ++i){
        int t = tid + i*256;
        float v = -1e30f;
        if (t <= s) v = __uint_as_float(((unsigned)r[t]) << 16);
        vals[i] = v; m = fmaxf(m, v);
    }
    #pragma unroll
    for (int off = 32; off > 0; off >>= 1) m = fmaxf(m, __shfl_down(m, off, 64));
    if ((tid & 63) == 0) red[tid >> 6] = m;
    __syncthreads();
    const float M4 = fmaxf(fmaxf(red[0],red[1]), fmaxf(red[2],red[3]));
    __syncthreads();
    float ev[8]; float sum = 0.f;
    #pragma unroll
    for (int i = 0; i < 8; ++i){ ev[i] = __expf(vals[i] - M4); sum += ev[i]; }
    #pragma unroll
    for (int off = 32; off > 0; off >>= 1) sum += __shfl_down(sum, off, 64);
    if ((tid & 63) == 0) red[tid >> 6] = sum;
    __syncthreads();
    const float inv = 1.0f / (red[0]+red[1]+red[2]+red[3]);
    #pragma unroll
    for (int i = 0; i < 8; ++i){
        int t = tid + i*256;
        if (t < width) r[t] = f2bfbits(ev[i] * inv);
    }
}

// ---------- ctx = P @ V ; A=packed P (zpad for masked rows), B=VT[d][tok] ----------
__global__ __launch_bounds__(256)
void pv_mfma(const unsigned short* __restrict__ Pb, const unsigned short* __restrict__ VT,
             unsigned short* __restrict__ Cb, const unsigned short* __restrict__ zpad)
{
    const int3 b = xcd_swz();
    const int s0 = b.y*128, n0 = b.x*128;
    const unsigned short* P = Pb + (size_t)b.z*PPB;
    unsigned short* C       = Cb + (size_t)b.z*SD;
    const int bcol = b.z*SS;
    __shared__ unsigned short As[128*64];
    __shared__ unsigned short Bs[128*64];
    const int tid = threadIdx.x, lane = tid & 63, wave = tid >> 6;
    const int wm = ((wave >> 1) & 1) * 64, wn = (wave & 1) * 64;
    const int quad = lane >> 4, l15 = lane & 15;
    const unsigned short* ga[4]; const unsigned short* gb[4]; int pw[4];
    #pragma unroll
    for (int c = 0; c < 4; ++c){
        const int mr = (wave*4 + c)*8 + (lane >> 3);
        const int gk = ((lane & 7) - mr) & 7;
        const int s = s0 + mr;
        pw[c] = rowWidth(s) - gk*8;                 // valid iff k0 < pw (both mult of 64 logic holds)
        ga[c] = P + rowOff(s) + gk*8;
        gb[c] = VT + (size_t)(n0 + mr)*MM + bcol + gk*8;
    }
    f32x4 acc[4][4] = {};
    const int kmax = s0 + 128;
    for (int k0 = 0; k0 < kmax; k0 += 64){
        #pragma unroll
        for (int c = 0; c < 4; ++c){
            const unsigned short* gp = (k0 < pw[c]) ? (ga[c] + k0) : zpad;
            gl_lds(gp, &As[(wave*4+c)*512]);
            gl_lds(gb[c] + k0, &Bs[(wave*4+c)*512]);
        }
        __syncthreads();
        #pragma unroll
        for (int kk = 0; kk < 2; ++kk){
            bf16x8 af[4], bfr[4];
            #pragma unroll
            for (int t = 0; t < 4; ++t){
                const int ra = wm + t*16 + l15, rb = wn + t*16 + l15, gi = kk*4 + quad;
                af[t]  = *(const bf16x8*)&As[ra*64 + (((gi + ra) & 7) << 3)];
                bfr[t] = *(const bf16x8*)&Bs[rb*64 + (((gi + rb) & 7) << 3)];
            }
            #pragma unroll
            for (int i = 0; i < 4; ++i)
                #pragma unroll
                for (int j = 0; j < 4; ++j)
                    acc[i][j] = __builtin_amdgcn_mfma_f32_16x16x32_bf16(af[i], bfr[j], acc[i][j], 0, 0, 0);
        }
        __syncthreads();
    }
    #pragma unroll
    for (int i = 0; i < 4; ++i){
        #pragma unroll
        for (int r = 0; r < 4; ++r){
            const int s = s0 + wm + i*16 + quad*4 + r;
            #pragma unroll
            for (int j = 0; j < 4; ++j){
                const int n = n0 + wn + j*16 + l15;
                C[(size_t)s*DD + n] = f2bfbits(acc[i][j][r]);
            }
        }
    }
}

extern "C" void kernel_launch(void* const* d_in, const int* in_sizes, int n_in,
                              void* d_out, int out_size, void* d_ws, size_t ws_size,
                              hipStream_t stream)
{
    (void)in_sizes; (void)n_in; (void)out_size;
    const float* x   = (const float*)d_in[0];
    const float* bq  = (const float*)d_in[2];
    const float* bk  = (const float*)d_in[4];
    const float* bv  = (const float*)d_in[6];
    const float* bo  = (const float*)d_in[8];
    const float* b1  = (const float*)d_in[10];
    const float* b2  = (const float*)d_in[12];
    const float* g1  = (const float*)d_in[13];
    const float* be1 = (const float*)d_in[14];
    const float* g2  = (const float*)d_in[15];
    const float* be2 = (const float*)d_in[16];
    float* outf = (float*)d_out;

    if (ws_size < (size_t)REQ_WS){
        sentinel_kernel<<<dim3((unsigned)(MD/256)), dim3(256), 0, stream>>>(outf, 1.0e9f);
        return;
    }

    unsigned short* wsb = (unsigned short*)d_ws;
    unsigned short* Qw  = wsb;                 // -> ctx
    unsigned short* Kw  = wsb + MD;            // \ -> Hf (fp32 spans K+VT)
    unsigned short* VTw = wsb + 2*MD;          // /
    unsigned short* Pw  = wsb + 3*MD;          // packed P -> mid
    unsigned short* WT  = wsb + WT_OFF;
    unsigned short* ZP  = wsb + ZP_OFF;
    float*          Hf  = (float*)Kw;
    unsigned short* CTX = Qw;
    unsigned short* MIDw= Pw;
    unsigned short* LN  = (unsigned short*)d_out;   // LN1/LN2 scratch in d_out

    WPack wp;
    static const int widx[6] = {1,3,5,7,9,11};
    for (int i = 0; i < 6; ++i){
        wp.w[i] = (const float*)d_in[widx[i]];
        wp.o[i] = WT + (size_t)i*DD*DD;
    }
    wp.zp = ZP;
    unsigned short* WqT = wp.o[0]; unsigned short* WkT = wp.o[1];
    unsigned short* WvT = wp.o[2]; unsigned short* WoT = wp.o[3];
    unsigned short* W1T = wp.o[4]; unsigned short* W2T = wp.o[5];

    const dim3 blk(256);
    const float scale = 1.0f / sqrtf((float)SS);
    const dim3 gA(DD/128, MM/128);    // (8,64)
    const dim3 gVT(MM/128, DD/128);   // (64,8)

    wtrans<<<dim3(16,16,6), blk, 0, stream>>>(wp);
    ln_f32<<<dim3(MM), blk, 0, stream>>>(x, g1, be1, LN);
    // Q,K merged (1024 blocks)
    gemm_qk<<<dim3(DD/128, MM/128, 2), blk, 0, stream>>>(LN, WqT, WkT, bq, bk, Qw, Kw);
    // VT[d][tok] = WvT . LN^T (bias along m)
    gemm_mfma<false,false,false,true ><<<gVT, blk, 0, stream>>>(WvT, LN, bv, nullptr, VTw, nullptr, MM, DD, DD, DD);
    // attention
    scores_mfma<<<dim3(SS/128, SS/128, BB), blk, 0, stream>>>(Qw, Kw, Pw, scale);
    softmax_p<<<dim3(SS, BB), blk, 0, stream>>>(Pw);
    pv_mfma<<<dim3(DD/128, SS/128, BB), blk, 0, stream>>>(Pw, VTw, CTX, ZP);
    // h = ctx*WoT^T + bo + x (fp32)
    gemm_mfma<false,true,true,false><<<gA, blk, 0, stream>>>(CTX, WoT, bo, x, nullptr, Hf, DD, DD, DD, DD);
    ln_f32<<<dim3(MM), blk, 0, stream>>>(Hf, g2, be2, LN);
    // mid = relu(LN*W1T^T + b1)
    gemm_mfma<true,false,false,false><<<gA, blk, 0, stream>>>(LN, W1T, b1, nullptr, MIDw, nullptr, DD, DD, DD, DD);
    // out = mid*W2T^T + b2 + h
    gemm_mfma<false,true,true,false><<<gA, blk, 0, stream>>>(MIDw, W2T, b2, Hf, nullptr, outf, DD, DD, DD, DD);
}

// Round 2
// 375.046 us; speedup vs baseline: 1.0634x; 1.0302x over previous
//
#include <hip/hip_runtime.h>
#include <math.h>

#define BB 4
#define SS 2048
#define DD 1024
#define MM (BB*SS)                   // 8192
#define SD ((size_t)SS*DD)
#define MD ((size_t)MM*DD)           // 8,388,608
#define PPB ((size_t)2162688)        // packed P elems per batch

// ws (bf16 elems): Q@0 | K@MD | VT@2MD | P@3MD (4*PPB) | WT@3MD+4PPB (6*DD*DD) | zpad(16)
#define WT_OFF (3*MD + 4*PPB)
#define ZP_OFF (WT_OFF + 6*(size_t)DD*DD)
#define REQ_WS ((ZP_OFF + 16) * 2)

constexpr float LN_EPS = 1e-6f;

typedef __attribute__((ext_vector_type(8))) __bf16 bf16x8;
typedef __attribute__((ext_vector_type(4))) float f32x4;

__device__ __forceinline__ unsigned short f2bfbits(float f){
    unsigned u = __float_as_uint(f);
    u += 0x7FFFu + ((u >> 16) & 1u);   // RNE
    return (unsigned short)(u >> 16);
}
__device__ __forceinline__ int rowWidth(int s){ return ((s >> 6) + 1) << 6; }
__device__ __forceinline__ size_t rowOff(int s){
    int g = s >> 6;
    return (size_t)4096 * (size_t)((g * (g + 1)) >> 1) + (size_t)(s & 63) * (size_t)((g + 1) << 6);
}
// async global->LDS, 16B per lane; LDS dest = wave-uniform base + lane*16
__device__ __forceinline__ void gl_lds(const unsigned short* g, unsigned short* l){
    __builtin_amdgcn_global_load_lds(
        (const __attribute__((address_space(1))) unsigned int*)g,
        (__attribute__((address_space(3))) unsigned int*)l, 16, 0, 0);
}

// XCD-aware bijective block swizzle (T1): each of the 8 XCDs gets a
// contiguous chunk of the linearized grid -> neighbor tiles share L2.
// Valid because every MFMA launch here has (gx*gy*gz) % 8 == 0.
__device__ __forceinline__ int3 xcd_swz(){
    const int gx = gridDim.x, gy = gridDim.y, gz = gridDim.z;
    const int n = gx * gy * gz;
    int lin = blockIdx.x + gx * (blockIdx.y + gy * blockIdx.z);
    const int cpx = n >> 3;                 // n % 8 == 0 for all launches
    lin = (lin & 7) * cpx + (lin >> 3);     // bijection: XCD (lin&7) owns chunk
    int3 r;
    r.x = lin % gx; lin /= gx;
    r.y = lin % gy;
    r.z = lin / gy;
    return r;
}

__global__ __launch_bounds__(256)
void sentinel_kernel(float* __restrict__ out, const float val){
    out[(size_t)blockIdx.x * 256 + threadIdx.x] = val;
}

// ---------- weight transpose W[K][N] f32 -> WT[N][K] bf16 ; also zeroes zpad ----------
struct WPack { const float* w[6]; unsigned short* o[6]; unsigned short* zp; };
__global__ __launch_bounds__(256)
void wtrans(WPack wp)
{
    __shared__ float Ts[64][65];
    const float* W = wp.w[blockIdx.z];
    unsigned short* WT = wp.o[blockIdx.z];
    const int r0 = blockIdx.y*64, c0 = blockIdx.x*64;
    const int tid = threadIdx.x;
    if (blockIdx.x == 0 && blockIdx.y == 0 && blockIdx.z == 0 && tid < 16) wp.zp[tid] = 0;
    #pragma unroll
    for (int i = 0; i < 16; ++i){
        int lin = tid + i*256;
        int r = lin >> 6, c = lin & 63;
        Ts[r][c] = W[(size_t)(r0+r)*DD + c0+c];
    }
    __syncthreads();
    #pragma unroll
    for (int i = 0; i < 16; ++i){
        int lin = tid + i*256;
        int r = lin >> 6, c = lin & 63;
        WT[(size_t)(c0+r)*DD + r0+c] = f2bfbits(Ts[c][r]);
    }
}

// ---------- LayerNorm: fp32 in -> bf16 out ----------
__global__ __launch_bounds__(256)
void ln_f32(const float* __restrict__ x, const float* __restrict__ gamma,
            const float* __restrict__ beta, unsigned short* __restrict__ out)
{
    __shared__ float red[4];
    const int row = blockIdx.x;
    const int tid = threadIdx.x;
    float4 xv = ((const float4*)(x + (size_t)row*DD))[tid];
    float v[4] = {xv.x, xv.y, xv.z, xv.w};
    float s = v[0]+v[1]+v[2]+v[3];
    #pragma unroll
    for (int off = 32; off > 0; off >>= 1) s += __shfl_down(s, off, 64);
    if ((tid & 63) == 0) red[tid >> 6] = s;
    __syncthreads();
    const float mean = (red[0]+red[1]+red[2]+red[3]) * (1.0f/DD);
    __syncthreads();
    float q = 0.f;
    #pragma unroll
    for (int i = 0; i < 4; ++i){ float d = v[i]-mean; q += d*d; }
    #pragma unroll
    for (int off = 32; off > 0; off >>= 1) q += __shfl_down(q, off, 64);
    if ((tid & 63) == 0) red[tid >> 6] = q;
    __syncthreads();
    const float var = (red[0]+red[1]+red[2]+red[3]) * (1.0f/(DD-1));
    const float inv = 1.0f/(sqrtf(var) + LN_EPS);
    float4 g4 = ((const float4*)gamma)[tid];
    float4 b4 = ((const float4*)beta)[tid];
    ushort4 o;
    o.x = f2bfbits(g4.x*(v[0]-mean)*inv + b4.x);
    o.y = f2bfbits(g4.y*(v[1]-mean)*inv + b4.y);
    o.z = f2bfbits(g4.z*(v[2]-mean)*inv + b4.z);
    o.w = f2bfbits(g4.w*(v[3]-mean)*inv + b4.w);
    ((ushort4*)(out + (size_t)row*DD))[tid] = o;
}

// =========== 8-wave deep-pipelined GEMM core ===========
// C[256,128] tile of A[M,K]*B[N,K]^T. BK=64, 512 thr (8 waves 4Mx2N, each 64x64).
// Triple-buffered LDS (144KB), counted vmcnt(6) (T4), 2 phases/K-tile with
// raw-barrier + setprio MFMA clusters (T3+T5). Granule-rotated LDS (conflict-free).
template<bool RELU, bool RES, bool OUTF, bool BIAS_M>
__device__ __forceinline__ void gemm_core8(
    const unsigned short* __restrict__ A, const unsigned short* __restrict__ B,
    const float* __restrict__ bias, const float* __restrict__ resF,
    unsigned short* __restrict__ outB, float* __restrict__ outF,
    const int N, const int K, const int lda, const int ldb,
    const int m0, const int n0, unsigned short* S)
{
    // LDS layout (shorts): A0|A1|A2 (16384 each) then B0|B1|B2 (8192 each)
    unsigned short* A0 = S;
    unsigned short* A1 = S + 16384;
    unsigned short* A2 = S + 32768;
    unsigned short* B0 = S + 49152;
    unsigned short* B1 = S + 57344;
    unsigned short* B2 = S + 65536;

    const int tid = threadIdx.x, lane = tid & 63, wave = tid >> 6;
    const int wr = (wave >> 1) * 64;      // wave row offset in 256
    const int wc = (wave & 1) * 64;       // wave col offset in 128
    const int quad = lane >> 4, l15 = lane & 15;

    const unsigned short* ga[4]; const unsigned short* gb[2];
    #pragma unroll
    for (int c = 0; c < 4; ++c){
        const int mr = (wave*4 + c)*8 + (lane >> 3);          // 0..255
        const int gk = ((lane & 7) - mr) & 7;
        ga[c] = A + (size_t)(m0 + mr)*lda + gk*8;
    }
    #pragma unroll
    for (int c = 0; c < 2; ++c){
        const int mr = (wave*2 + c)*8 + (lane >> 3);          // 0..127
        const int gk = ((lane & 7) - mr) & 7;
        gb[c] = B + (size_t)(n0 + mr)*ldb + gk*8;
    }

    f32x4 acc[4][4] = {};
    const int NT = K >> 6;                 // = 16 here (K=1024)

    // prologue: stage tile0 -> A0/B0, tile1 -> A1/B1; wait tile0 only
    #pragma unroll
    for (int c = 0; c < 4; ++c) gl_lds(ga[c], &A0[(wave*4+c)*512]);
    #pragma unroll
    for (int c = 0; c < 2; ++c) gl_lds(gb[c], &B0[(wave*2+c)*512]);
    #pragma unroll
    for (int c = 0; c < 4; ++c) gl_lds(ga[c] + 64, &A1[(wave*4+c)*512]);
    #pragma unroll
    for (int c = 0; c < 2; ++c) gl_lds(gb[c] + 64, &B1[(wave*2+c)*512]);
    asm volatile("s_waitcnt vmcnt(6)" ::: "memory");
    __builtin_amdgcn_s_barrier();

    for (int t = 0; t < NT; ++t){
        const int kn = (t + 2) << 6;
        const bool more2 = (t + 2 < NT);
        #pragma unroll
        for (int kk = 0; kk < 2; ++kk){
            bf16x8 af[4], bfr[4];
            #pragma unroll
            for (int u = 0; u < 4; ++u){
                const int ra = wr + u*16 + l15, rb = wc + u*16 + l15, gi = kk*4 + quad;
                af[u]  = *(const bf16x8*)&A0[ra*64 + (((gi + ra) & 7) << 3)];
                bfr[u] = *(const bf16x8*)&B0[rb*64 + (((gi + rb) & 7) << 3)];
            }
            if (kk == 0 && more2){
                // stage tile t+2 into the free buffer (its last reader passed
                // the final barrier of iter t-1)
                #pragma unroll
                for (int c = 0; c < 4; ++c) gl_lds(ga[c] + kn, &A2[(wave*4+c)*512]);
                #pragma unroll
                for (int c = 0; c < 2; ++c) gl_lds(gb[c] + kn, &B2[(wave*2+c)*512]);
            }
            __builtin_amdgcn_s_barrier();
            asm volatile("s_waitcnt lgkmcnt(0)" ::: "memory");
            __builtin_amdgcn_sched_barrier(0);
            __builtin_amdgcn_s_setprio(1);
            #pragma unroll
            for (int i = 0; i < 4; ++i)
                #pragma unroll
                for (int j = 0; j < 4; ++j)
                    acc[i][j] = __builtin_amdgcn_mfma_f32_16x16x32_bf16(af[i], bfr[j], acc[i][j], 0, 0, 0);
            __builtin_amdgcn_s_setprio(0);
            if (kk == 1){
                // ensure tile t+1 (issued at iter t-1) has landed; keep the 6
                // loads for t+2 in flight (counted vmcnt - never 0 mid-loop)
                if (more2) asm volatile("s_waitcnt vmcnt(6)" ::: "memory");
                else       asm volatile("s_waitcnt vmcnt(0)" ::: "memory");
            }
            __builtin_amdgcn_s_barrier();
        }
        // rotate buffers: compute<-A1, inflight<-A2, free<-old compute
        unsigned short* ta = A0; A0 = A1; A1 = A2; A2 = ta;
        unsigned short* tb = B0; B0 = B1; B1 = B2; B2 = tb;
    }

    #pragma unroll
    for (int i = 0; i < 4; ++i){
        #pragma unroll
        for (int r = 0; r < 4; ++r){
            const int m = m0 + wr + i*16 + quad*4 + r;
            const float bm = BIAS_M ? bias[m] : 0.f;
            #pragma unroll
            for (int j = 0; j < 4; ++j){
                const int n = n0 + wc + j*16 + l15;
                float v = acc[i][j][r] + (BIAS_M ? bm : bias[n]);
                if constexpr (RELU) v = fmaxf(v, 0.f);
                if constexpr (RES) v += resF[(size_t)m*N + n];
                if constexpr (OUTF) outF[(size_t)m*N + n] = v;
                else outB[(size_t)m*N + n] = f2bfbits(v);
            }
        }
    }
}

// generic single GEMM (256x128 tiles, 512 threads)
template<bool RELU, bool RES, bool OUTF, bool BIAS_M>
__global__ __launch_bounds__(512)
void gemm_mfma(const unsigned short* __restrict__ A, const unsigned short* __restrict__ B,
               const float* __restrict__ bias, const float* __restrict__ resF,
               unsigned short* __restrict__ outB, float* __restrict__ outF,
               const int N, const int K, const int lda, const int ldb)
{
    __shared__ unsigned short Smem[73728];   // 144 KiB
    const int3 b = xcd_swz();
    gemm_core8<RELU,RES,OUTF,BIAS_M>(A, B, bias, resF, outB, outF, N, K, lda, ldb,
                                     b.y*256, b.x*128, Smem);
}

// merged Q+K projection (z=0 -> Q, z=1 -> K)
__global__ __launch_bounds__(512)
void gemm_qk(const unsigned short* __restrict__ LN,
             const unsigned short* __restrict__ WqT, const unsigned short* __restrict__ WkT,
             const float* __restrict__ bq, const float* __restrict__ bk,
             unsigned short* __restrict__ Qw, unsigned short* __restrict__ Kw)
{
    __shared__ unsigned short Smem[73728];   // 144 KiB
    const int3 b = xcd_swz();
    const bool isK = (b.z != 0);
    gemm_core8<false,false,false,false>(LN, isK ? WkT : WqT, isK ? bk : bq, nullptr,
                                        isK ? Kw : Qw, nullptr, DD, DD, DD, DD,
                                        b.y*256, b.x*128, Smem);
}

// ---------- scores: packed P = Q*K^T * scale (causal block-skip) ----------
__global__ __launch_bounds__(256)
void scores_mfma(const unsigned short* __restrict__ Qb, const unsigned short* __restrict__ Kb,
                 unsigned short* __restrict__ Pb, const float scale)
{
    const int3 b = xcd_swz();
    const int s0 = b.y*128, t0 = b.x*128;
    if (t0 > s0) return;
    const unsigned short* Q  = Qb + (size_t)b.z*SD;
    const unsigned short* Km = Kb + (size_t)b.z*SD;
    unsigned short* P        = Pb + (size_t)b.z*PPB;
    __shared__ unsigned short As[128*64];
    __shared__ unsigned short Bs[128*64];
    const int tid = threadIdx.x, lane = tid & 63, wave = tid >> 6;
    const int wm = ((wave >> 1) & 1) * 64, wn = (wave & 1) * 64;
    const int quad = lane >> 4, l15 = lane & 15;
    const unsigned short* ga[4]; const unsigned short* gb[4];
    #pragma unroll
    for (int c = 0; c < 4; ++c){
        const int mr = (wave*4 + c)*8 + (lane >> 3);
        const int gk = ((lane & 7) - mr) & 7;
        ga[c] = Q  + (size_t)(s0 + mr)*DD + gk*8;
        gb[c] = Km + (size_t)(t0 + mr)*DD + gk*8;
    }
    f32x4 acc[4][4] = {};
    for (int k0 = 0; k0 < DD; k0 += 64){
        #pragma unroll
        for (int c = 0; c < 4; ++c){
            gl_lds(ga[c] + k0, &As[(wave*4+c)*512]);
            gl_lds(gb[c] + k0, &Bs[(wave*4+c)*512]);
        }
        __syncthreads();
        #pragma unroll
        for (int kk = 0; kk < 2; ++kk){
            bf16x8 af[4], bfr[4];
            #pragma unroll
            for (int t = 0; t < 4; ++t){
                const int ra = wm + t*16 + l15, rb = wn + t*16 + l15, gi = kk*4 + quad;
                af[t]  = *(const bf16x8*)&As[ra*64 + (((gi + ra) & 7) << 3)];
                bfr[t] = *(const bf16x8*)&Bs[rb*64 + (((gi + rb) & 7) << 3)];
            }
            #pragma unroll
            for (int i = 0; i < 4; ++i)
                #pragma unroll
                for (int j = 0; j < 4; ++j)
                    acc[i][j] = __builtin_amdgcn_mfma_f32_16x16x32_bf16(af[i], bfr[j], acc[i][j], 0, 0, 0);
        }
        __syncthreads();
    }
    #pragma unroll
    for (int i = 0; i < 4; ++i){
        #pragma unroll
        for (int r = 0; r < 4; ++r){
            const int s = s0 + wm + i*16 + quad*4 + r;
            const int width = rowWidth(s);
            unsigned short* pr = P + rowOff(s);
            #pragma unroll
            for (int j = 0; j < 4; ++j){
                const int t = t0 + wn + j*16 + l15;
                if (t < width) pr[t] = f2bfbits(acc[i][j][r] * scale);
            }
        }
    }
}

// ---------- causal softmax over packed rows ----------
__global__ __launch_bounds__(256)
void softmax_p(unsigned short* __restrict__ Pb)
{
    __shared__ float red[4];
    const int s = blockIdx.x;
    const int width = rowWidth(s);
    unsigned short* r = Pb + (size_t)blockIdx.y * PPB + rowOff(s);
    const int tid = threadIdx.x;
    float vals[8];
    float m = -1e30f;
    #pragma unroll
    for (int i = 0; i < 8; ++i){
        int t = tid + i*256;
        float v = -1e30f;
        if (t <= s) v = __uint_as_float(((unsigned)r[t]) << 16);
        vals[i] = v; m = fmaxf(m, v);
    }
    #pragma unroll
    for (int off = 32; off > 0; off >>= 1) m = fmaxf(m, __shfl_down(m, off, 64));
    if ((tid & 63) == 0) red[tid >> 6] = m;
    __syncthreads();
    const float M4 = fmaxf(fmaxf(red[0],red[1]), fmaxf(red[2],red[3]));
    __syncthreads();
    float ev[8]; float sum = 0.f;
    #pragma unroll
    for (int i = 0; i < 8; ++i){ ev[i] = __expf(vals[i] - M4); sum += ev[i]; }
    #pragma unroll
    for (int off = 32; off > 0; off >>= 1) sum += __shfl_down(sum, off, 64);
    if ((tid & 63) == 0) red[tid >> 6] = sum;
    __syncthreads();
    const float inv = 1.0f / (red[0]+red[1]+red[2]+red[3]);
    #pragma unroll
    for (int i = 0; i < 8; ++i){
        int t = tid + i*256;
        if (t < width) r[t] = f2bfbits(ev[i] * inv);
    }
}

// ---------- ctx = P @ V ; A=packed P (zpad for masked rows), B=VT[d][tok] ----------
__global__ __launch_bounds__(256)
void pv_mfma(const unsigned short* __restrict__ Pb, const unsigned short* __restrict__ VT,
             unsigned short* __restrict__ Cb, const unsigned short* __restrict__ zpad)
{
    const int3 b = xcd_swz();
    const int s0 = b.y*128, n0 = b.x*128;
    const unsigned short* P = Pb + (size_t)b.z*PPB;
    unsigned short* C       = Cb + (size_t)b.z*SD;
    const int bcol = b.z*SS;
    __shared__ unsigned short As[128*64];
    __shared__ unsigned short Bs[128*64];
    const int tid = threadIdx.x, lane = tid & 63, wave = tid >> 6;
    const int wm = ((wave >> 1) & 1) * 64, wn = (wave & 1) * 64;
    const int quad = lane >> 4, l15 = lane & 15;
    const unsigned short* ga[4]; const unsigned short* gb[4]; int pw[4];
    #pragma unroll
    for (int c = 0; c < 4; ++c){
        const int mr = (wave*4 + c)*8 + (lane >> 3);
        const int gk = ((lane & 7) - mr) & 7;
        const int s = s0 + mr;
        pw[c] = rowWidth(s) - gk*8;                 // valid iff k0 < pw (both mult of 64 logic holds)
        ga[c] = P + rowOff(s) + gk*8;
        gb[c] = VT + (size_t)(n0 + mr)*MM + bcol + gk*8;
    }
    f32x4 acc[4][4] = {};
    const int kmax = s0 + 128;
    for (int k0 = 0; k0 < kmax; k0 += 64){
        #pragma unroll
        for (int c = 0; c < 4; ++c){
            const unsigned short* gp = (k0 < pw[c]) ? (ga[c] + k0) : zpad;
            gl_lds(gp, &As[(wave*4+c)*512]);
            gl_lds(gb[c] + k0, &Bs[(wave*4+c)*512]);
        }
        __syncthreads();
        #pragma unroll
        for (int kk = 0; kk < 2; ++kk){
            bf16x8 af[4], bfr[4];
            #pragma unroll
            for (int t = 0; t < 4; ++t){
                const int ra = wm + t*16 + l15, rb = wn + t*16 + l15, gi = kk*4 + quad;
                af[t]  = *(const bf16x8*)&As[ra*64 + (((gi + ra) & 7) << 3)];
                bfr[t] = *(const bf16x8*)&Bs[rb*64 + (((gi + rb) & 7) << 3)];
            }
            #pragma unroll
            for (int i = 0; i < 4; ++i)
                #pragma unroll
                for (int j = 0; j < 4; ++j)
                    acc[i][j] = __builtin_amdgcn_mfma_f32_16x16x32_bf16(af[i], bfr[j], acc[i][j], 0, 0, 0);
        }
        __syncthreads();
    }
    #pragma unroll
    for (int i = 0; i < 4; ++i){
        #pragma unroll
        for (int r = 0; r < 4; ++r){
            const int s = s0 + wm + i*16 + quad*4 + r;
            #pragma unroll
            for (int j = 0; j < 4; ++j){
                const int n = n0 + wn + j*16 + l15;
                C[(size_t)s*DD + n] = f2bfbits(acc[i][j][r]);
            }
        }
    }
}

extern "C" void kernel_launch(void* const* d_in, const int* in_sizes, int n_in,
                              void* d_out, int out_size, void* d_ws, size_t ws_size,
                              hipStream_t stream)
{
    (void)in_sizes; (void)n_in; (void)out_size;
    const float* x   = (const float*)d_in[0];
    const float* bq  = (const float*)d_in[2];
    const float* bk  = (const float*)d_in[4];
    const float* bv  = (const float*)d_in[6];
    const float* bo  = (const float*)d_in[8];
    const float* b1  = (const float*)d_in[10];
    const float* b2  = (const float*)d_in[12];
    const float* g1  = (const float*)d_in[13];
    const float* be1 = (const float*)d_in[14];
    const float* g2  = (const float*)d_in[15];
    const float* be2 = (const float*)d_in[16];
    float* outf = (float*)d_out;

    if (ws_size < (size_t)REQ_WS){
        sentinel_kernel<<<dim3((unsigned)(MD/256)), dim3(256), 0, stream>>>(outf, 1.0e9f);
        return;
    }

    unsigned short* wsb = (unsigned short*)d_ws;
    unsigned short* Qw  = wsb;                 // -> ctx
    unsigned short* Kw  = wsb + MD;            // \ -> Hf (fp32 spans K+VT)
    unsigned short* VTw = wsb + 2*MD;          // /
    unsigned short* Pw  = wsb + 3*MD;          // packed P -> mid
    unsigned short* WT  = wsb + WT_OFF;
    unsigned short* ZP  = wsb + ZP_OFF;
    float*          Hf  = (float*)Kw;
    unsigned short* CTX = Qw;
    unsigned short* MIDw= Pw;
    unsigned short* LN  = (unsigned short*)d_out;   // LN1/LN2 scratch in d_out

    WPack wp;
    static const int widx[6] = {1,3,5,7,9,11};
    for (int i = 0; i < 6; ++i){
        wp.w[i] = (const float*)d_in[widx[i]];
        wp.o[i] = WT + (size_t)i*DD*DD;
    }
    wp.zp = ZP;
    unsigned short* WqT = wp.o[0]; unsigned short* WkT = wp.o[1];
    unsigned short* WvT = wp.o[2]; unsigned short* WoT = wp.o[3];
    unsigned short* W1T = wp.o[4]; unsigned short* W2T = wp.o[5];

    const dim3 blk(256);
    const dim3 blk8(512);
    const float scale = 1.0f / sqrtf((float)SS);
    const dim3 gA8(DD/128, MM/256);   // (8,32)  = 256 blocks
    const dim3 gVT8(MM/128, DD/256);  // (64,4)  = 256 blocks

    wtrans<<<dim3(16,16,6), blk, 0, stream>>>(wp);
    ln_f32<<<dim3(MM), blk, 0, stream>>>(x, g1, be1, LN);
    // Q,K merged (512 blocks of 512 thr)
    gemm_qk<<<dim3(DD/128, MM/256, 2), blk8, 0, stream>>>(LN, WqT, WkT, bq, bk, Qw, Kw);
    // VT[d][tok] = WvT . LN^T (bias along m)
    gemm_mfma<false,false,false,true ><<<gVT8, blk8, 0, stream>>>(WvT, LN, bv, nullptr, VTw, nullptr, MM, DD, DD, DD);
    // attention
    scores_mfma<<<dim3(SS/128, SS/128, BB), blk, 0, stream>>>(Qw, Kw, Pw, scale);
    softmax_p<<<dim3(SS, BB), blk, 0, stream>>>(Pw);
    pv_mfma<<<dim3(DD/128, SS/128, BB), blk, 0, stream>>>(Pw, VTw, CTX, ZP);
    // h = ctx*WoT^T + bo + x (fp32)
    gemm_mfma<false,true,true,false><<<gA8, blk8, 0, stream>>>(CTX, WoT, bo, x, nullptr, Hf, DD, DD, DD, DD);
    ln_f32<<<dim3(MM), blk, 0, stream>>>(Hf, g2, be2, LN);
    // mid = relu(LN*W1T^T + b1)
    gemm_mfma<true,false,false,false><<<gA8, blk8, 0, stream>>>(LN, W1T, b1, nullptr, MIDw, nullptr, DD, DD, DD, DD);
    // out = mid*W2T^T + b2 + h
    gemm_mfma<false,true,true,false><<<gA8, blk8, 0, stream>>>(MIDw, W2T, b2, Hf, nullptr, outf, DD, DD, DD, DD);
}